// Round 3
// baseline (548.448 us; speedup 1.0000x reference)
//
#include <hip/hip_runtime.h>
#include <math.h>

#define N_NODES 50000
#define E_EDGES 800000
#define ETOT    850000   // E + N self loops
#define NEG     0.2f

// ---------------------------------------------------------------- CSR build
__global__ __launch_bounds__(256) void k_init(int* counts, float* mean) {
  int i = blockIdx.x * 256 + threadIdx.x;
  if (i < N_NODES) counts[i] = 1;          // reserve rank 0 for self loop
  if (i < 16) mean[i] = 0.f;
}

__global__ __launch_bounds__(256) void k_count(const int* __restrict__ ei, int* counts, int* rank) {
  int e = blockIdx.x * 256 + threadIdx.x;
  if (e >= E_EDGES) return;
  int d = ei[E_EDGES + e];
  rank[e] = atomicAdd(&counts[d], 1);
}

__global__ __launch_bounds__(256) void k_scan1(const int* __restrict__ counts, int* offs, int* bsum) {
  __shared__ int lds[256];
  int t = threadIdx.x;
  int i = blockIdx.x * 256 + t;
  int v = (i < N_NODES) ? counts[i] : 0;
  lds[t] = v;
  __syncthreads();
  for (int s = 1; s < 256; s <<= 1) {
    int add = (t >= s) ? lds[t - s] : 0;
    __syncthreads();
    lds[t] += add;
    __syncthreads();
  }
  if (i < N_NODES) offs[i] = lds[t] - v;   // exclusive within chunk
  if (t == 255) bsum[blockIdx.x] = lds[255];
}

__global__ __launch_bounds__(256) void k_scan2(int* bsum, int nb) {
  __shared__ int lds[256];
  int t = threadIdx.x;
  int v = (t < nb) ? bsum[t] : 0;
  lds[t] = v;
  __syncthreads();
  for (int s = 1; s < 256; s <<= 1) {
    int add = (t >= s) ? lds[t - s] : 0;
    __syncthreads();
    lds[t] += add;
    __syncthreads();
  }
  if (t < nb) bsum[t] = lds[t] - v;        // exclusive chunk bases
}

__global__ __launch_bounds__(256) void k_scan3(int* offs, const int* __restrict__ bsum) {
  int i = blockIdx.x * 256 + threadIdx.x;
  if (i < N_NODES) offs[i] += bsum[i >> 8];
  if (i == 0) offs[N_NODES] = ETOT;
}

__global__ __launch_bounds__(256) void k_fill(const int* __restrict__ ei, const int* __restrict__ rank,
                                              const int* __restrict__ offs,
                                              int* srcp, int* dstp, int* eidp) {
  int idx = blockIdx.x * 256 + threadIdx.x;
  if (idx < E_EDGES) {
    int d = ei[E_EDGES + idx];
    int pos = offs[d] + rank[idx];
    srcp[pos] = ei[idx];
    dstp[pos] = d;
    eidp[pos] = idx;
  } else if (idx < ETOT) {
    int n2 = idx - E_EDGES;
    int pos = offs[n2];                    // self loop at rank 0
    srcp[pos] = n2;
    dstp[pos] = n2;
    eidp[pos] = E_EDGES + n2;              // marker: use mean edge_attr
  }
}

// ------------------------------------------------------- edge-attr mean, W_edge·att_edge
__global__ __launch_bounds__(256) void k_meansum(const float* __restrict__ ea, float* mean) {
  __shared__ float lds[256];
  int t = threadIdx.x;
  float s = 0.f;
  const int total = E_EDGES * 16;
  for (int i = blockIdx.x * 256 + t; i < total; i += gridDim.x * 256) s += ea[i];
  lds[t] = s;                               // column = t & 15 (strides are multiples of 16)
  __syncthreads();
  for (int h = 128; h >= 16; h >>= 1) { if (t < h) lds[t] += lds[t + h]; __syncthreads(); }
  if (t < 16) atomicAdd(&mean[t], lds[t] * (1.0f / E_EDGES));
}

// wea[l][d][h] = sum_c W_edge[l][d][h*32+c] * att_edge[l][h][c]
__global__ void k_wea(const float* __restrict__ W_edge, const float* __restrict__ att_edge, float* wea) {
  int t = threadIdx.x;
  if (t >= 192) return;
  int l = t >> 6, rem = t & 63, d = rem >> 2, h = rem & 3;
  const float* wp = W_edge + l * 2048 + d * 128 + h * 32;
  const float* ap = att_edge + l * 128 + h * 32;
  float s = 0.f;
  for (int c = 0; c < 32; ++c) s += wp[c] * ap[c];
  wea[t] = s;
}

// ---------------------------------------------------------------- GEMM  Y[N,128] = X[N,128] @ W[128,128]
__global__ __launch_bounds__(256) void k_gemm(const float* __restrict__ X, const float* __restrict__ Wl,
                                              float* __restrict__ Y) {
  __shared__ float ws_[64 * 128];          // 32 KB: half of W's K-rows at a time
  int tid = threadIdx.x;
  int ty = tid >> 4, tx = tid & 15;        // 16x16 threads; 2 rows x 8 cols each
  int r0 = blockIdx.x * 32 + ty * 2;
  int ra = min(r0, N_NODES - 1), rb = min(r0 + 1, N_NODES - 1);
  const float* xa = X + (long long)ra * 128;
  const float* xb = X + (long long)rb * 128;
  float acc[2][8];
#pragma unroll
  for (int i = 0; i < 2; ++i)
#pragma unroll
    for (int j = 0; j < 8; ++j) acc[i][j] = 0.f;

  for (int half = 0; half < 2; ++half) {
    __syncthreads();
#pragma unroll
    for (int i = 0; i < 8; ++i) {
      int f4 = tid + i * 256;              // 2048 float4 = 64x128 floats
      *(float4*)&ws_[f4 * 4] = *(const float4*)(Wl + half * 8192 + f4 * 4);
    }
    __syncthreads();
#pragma unroll 4
    for (int k4 = 0; k4 < 16; ++k4) {
      float4 a0 = *(const float4*)(xa + half * 64 + k4 * 4);
      float4 a1 = *(const float4*)(xb + half * 64 + k4 * 4);
      const float* av0 = (const float*)&a0;
      const float* av1 = (const float*)&a1;
#pragma unroll
      for (int kk = 0; kk < 4; ++kk) {
        const float* wk = ws_ + (k4 * 4 + kk) * 128 + tx * 8;
        float4 w0 = *(const float4*)(wk);
        float4 w1 = *(const float4*)(wk + 4);
        float x0 = av0[kk], x1 = av1[kk];
        acc[0][0] += x0 * w0.x; acc[0][1] += x0 * w0.y; acc[0][2] += x0 * w0.z; acc[0][3] += x0 * w0.w;
        acc[0][4] += x0 * w1.x; acc[0][5] += x0 * w1.y; acc[0][6] += x0 * w1.z; acc[0][7] += x0 * w1.w;
        acc[1][0] += x1 * w0.x; acc[1][1] += x1 * w0.y; acc[1][2] += x1 * w0.z; acc[1][3] += x1 * w0.w;
        acc[1][4] += x1 * w1.x; acc[1][5] += x1 * w1.y; acc[1][6] += x1 * w1.z; acc[1][7] += x1 * w1.w;
      }
    }
  }
  if (r0 < N_NODES) {
    float4* yp = (float4*)(Y + (long long)r0 * 128 + tx * 8);
    yp[0] = make_float4(acc[0][0], acc[0][1], acc[0][2], acc[0][3]);
    yp[1] = make_float4(acc[0][4], acc[0][5], acc[0][6], acc[0][7]);
  }
  if (r0 + 1 < N_NODES) {
    float4* yp = (float4*)(Y + (long long)(r0 + 1) * 128 + tx * 8);
    yp[0] = make_float4(acc[1][0], acc[1][1], acc[1][2], acc[1][3]);
    yp[1] = make_float4(acc[1][4], acc[1][5], acc[1][6], acc[1][7]);
  }
}

// ------------------------------------------------- per-node attention dots  as/ad[n][h]
__global__ __launch_bounds__(256) void k_attdot(const float* __restrict__ H, const float* __restrict__ att_s,
                                                const float* __restrict__ att_d, float* as_, float* ad_) {
  int t = threadIdx.x;
  int n2 = blockIdx.x * 2 + (t >> 7);
  int comp = t & 127;
  if (n2 >= N_NODES) return;
  float hv = H[(long long)n2 * 128 + comp];
  float vs = hv * att_s[comp];
  float vd = hv * att_d[comp];
#pragma unroll
  for (int m = 16; m >= 1; m >>= 1) {
    vs += __shfl_xor(vs, m);
    vd += __shfl_xor(vd, m);
  }
  if ((comp & 31) == 0) {
    as_[n2 * 4 + (comp >> 5)] = vs;
    ad_[n2 * 4 + (comp >> 5)] = vd;
  }
}

// ------------------------------------------------- per-edge logits (CSR order, post-leakyrelu)
__global__ __launch_bounds__(256) void k_edgealpha(const int* __restrict__ srcp, const int* __restrict__ dstp,
                                                   const int* __restrict__ eidp,
                                                   const float* __restrict__ edge_attr,
                                                   const float* __restrict__ mean,
                                                   const float* __restrict__ wea_l,
                                                   const float* __restrict__ as_, const float* __restrict__ ad_,
                                                   float* __restrict__ alpha) {
  __shared__ float wl[64];
  int t = threadIdx.x;
  if (t < 64) wl[t] = wea_l[t];
  __syncthreads();
  int pos = blockIdx.x * 256 + t;
  if (pos >= ETOT) return;
  int eid = eidp[pos], s = srcp[pos], d = dstp[pos];
  const float* ef = (eid < E_EDGES) ? (edge_attr + (long long)eid * 16) : mean;
  float a0 = 0, a1 = 0, a2 = 0, a3 = 0;
#pragma unroll
  for (int j = 0; j < 16; ++j) {
    float e = ef[j];
    a0 += e * wl[j * 4 + 0];
    a1 += e * wl[j * 4 + 1];
    a2 += e * wl[j * 4 + 2];
    a3 += e * wl[j * 4 + 3];
  }
  const float* asp = as_ + s * 4;
  const float* adp = ad_ + d * 4;
  float v0 = a0 + asp[0] + adp[0];
  float v1 = a1 + asp[1] + adp[1];
  float v2 = a2 + asp[2] + adp[2];
  float v3 = a3 + asp[3] + adp[3];
  alpha[pos * 4 + 0] = v0 > 0.f ? v0 : NEG * v0;
  alpha[pos * 4 + 1] = v1 > 0.f ? v1 : NEG * v1;
  alpha[pos * 4 + 2] = v2 > 0.f ? v2 : NEG * v2;
  alpha[pos * 4 + 3] = v3 > 0.f ? v3 : NEG * v3;
}

// ------------------------------------------------- aggregation: one wave per node, no atomics
__global__ __launch_bounds__(256) void k_agg(const float* __restrict__ H, const float* __restrict__ alpha,
                                             const int* __restrict__ offs, const int* __restrict__ srcp,
                                             const float* __restrict__ bias, float* __restrict__ out, int last) {
  int tid = threadIdx.x;
  int l = tid & 63;
  int n2 = blockIdx.x * 4 + (tid >> 6);
  if (n2 >= N_NODES) return;
  int off0 = offs[n2], off1 = offs[n2 + 1];
  int deg = off1 - off0;

  // pass 1: online softmax stats, lanes parallel over (edge,head); head = l&3
  float m = -INFINITY, s = 0.f;
  for (int t = l; t < deg * 4; t += 64) {
    float a = alpha[off0 * 4 + t];
    if (a > m) { s = s * __expf(m - a) + 1.f; m = a; }
    else s += __expf(a - m);
  }
#pragma unroll
  for (int msk = 4; msk <= 32; msk <<= 1) {
    float mo = __shfl_xor(m, msk);
    float so = __shfl_xor(s, msk);
    float nm = fmaxf(m, mo);
    float e1 = (m == -INFINITY) ? 0.f : __expf(m - nm);
    float e2 = (mo == -INFINITY) ? 0.f : __expf(mo - nm);
    s = s * e1 + so * e2;
    m = nm;
  }
  int h0 = l >> 5;                          // lane owns components l (head h0) and l+64 (head h0+2)
  float m0 = __shfl(m, h0), s0 = __shfl(s, h0);
  float m1 = __shfl(m, h0 + 2), s1 = __shfl(s, h0 + 2);

  // pass 2: gather + weighted accumulate
  float acc0 = 0.f, acc1 = 0.f;
#pragma unroll 2
  for (int j = 0; j < deg; ++j) {
    int pos = off0 + j;
    int src = srcp[pos];
    float c0 = __expf(alpha[pos * 4 + h0] - m0);
    float c1 = __expf(alpha[pos * 4 + h0 + 2] - m1);
    const float* hp = H + (long long)src * 128;
    acc0 += c0 * hp[l];
    acc1 += c1 * hp[64 + l];
  }
  acc0 /= (s0 + 1e-16f);
  acc1 /= (s1 + 1e-16f);

  if (!last) {
    out[(long long)n2 * 128 + l]      = acc0 + bias[l];
    out[(long long)n2 * 128 + 64 + l] = acc1 + bias[64 + l];
  } else {
    float tsum = acc0 + acc1;               // heads h0 and h0+2, channel l&31
    tsum += __shfl_xor(tsum, 32);           // add heads h0^1 and (h0^1)+2
    if (l < 32) out[(long long)n2 * 32 + l] = 0.25f * tsum + bias[l];
  }
}

// ---------------------------------------------------------------- launch
extern "C" void kernel_launch(void* const* d_in, const int* in_sizes, int n_in,
                              void* d_out, int out_size, void* d_ws, size_t ws_size,
                              hipStream_t stream) {
  const float* x         = (const float*)d_in[0];
  const float* edge_attr = (const float*)d_in[1];
  const int*   ei        = (const int*)d_in[2];
  const float* W         = (const float*)d_in[3];
  const float* att_src   = (const float*)d_in[4];
  const float* att_dst   = (const float*)d_in[5];
  const float* W_edge    = (const float*)d_in[6];
  const float* att_edge  = (const float*)d_in[7];
  const float* bias_cat  = (const float*)d_in[8];
  const float* bias_last = (const float*)d_in[9];

  char* w = (char*)d_ws;
  auto alloc = [&](size_t bytes) { char* p = w; w += (bytes + 255) & ~(size_t)255; return p; };
  float* A     = (float*)alloc(sizeof(float) * (size_t)N_NODES * 128);
  float* B     = (float*)alloc(sizeof(float) * (size_t)N_NODES * 128);
  float* alpha = (float*)alloc(sizeof(float) * (size_t)ETOT * 4);
  float* as_   = (float*)alloc(sizeof(float) * N_NODES * 4);
  float* ad_   = (float*)alloc(sizeof(float) * N_NODES * 4);
  float* meanv = (float*)alloc(sizeof(float) * 16);
  float* weav  = (float*)alloc(sizeof(float) * 192);
  int* counts  = (int*)alloc(sizeof(int) * N_NODES);
  int* offs    = (int*)alloc(sizeof(int) * (N_NODES + 1));
  int* srcp    = (int*)alloc(sizeof(int) * ETOT);
  int* dstp    = (int*)alloc(sizeof(int) * ETOT);
  int* eidp    = (int*)alloc(sizeof(int) * ETOT);
  int* bsum    = (int*)alloc(sizeof(int) * 256);
  int* rank    = (int*)alpha;              // alias: rank dead before alpha is first written

  const int nbN = (N_NODES + 255) / 256;   // 196

  hipLaunchKernelGGL(k_init,  dim3(nbN), dim3(256), 0, stream, counts, meanv);
  hipLaunchKernelGGL(k_count, dim3((E_EDGES + 255) / 256), dim3(256), 0, stream, ei, counts, rank);
  hipLaunchKernelGGL(k_scan1, dim3(nbN), dim3(256), 0, stream, counts, offs, bsum);
  hipLaunchKernelGGL(k_scan2, dim3(1),   dim3(256), 0, stream, bsum, nbN);
  hipLaunchKernelGGL(k_scan3, dim3(nbN), dim3(256), 0, stream, offs, bsum);
  hipLaunchKernelGGL(k_fill,  dim3((ETOT + 255) / 256), dim3(256), 0, stream, ei, rank, offs, srcp, dstp, eidp);
  hipLaunchKernelGGL(k_meansum, dim3(256), dim3(256), 0, stream, edge_attr, meanv);
  hipLaunchKernelGGL(k_wea,   dim3(1), dim3(256), 0, stream, W_edge, att_edge, weav);

  const float* hin = x;
  for (int lyr = 0; lyr < 3; ++lyr) {
    int last = (lyr == 2);
    hipLaunchKernelGGL(k_gemm, dim3((N_NODES + 31) / 32), dim3(256), 0, stream,
                       hin, W + lyr * 16384, A);
    hipLaunchKernelGGL(k_attdot, dim3(N_NODES / 2), dim3(256), 0, stream,
                       A, att_src + lyr * 128, att_dst + lyr * 128, as_, ad_);
    hipLaunchKernelGGL(k_edgealpha, dim3((ETOT + 255) / 256), dim3(256), 0, stream,
                       srcp, dstp, eidp, edge_attr, meanv, weav + lyr * 64, as_, ad_, alpha);
    hipLaunchKernelGGL(k_agg, dim3((N_NODES + 3) / 4), dim3(256), 0, stream,
                       A, alpha, offs, srcp,
                       last ? bias_last : (bias_cat + lyr * 128),
                       last ? (float*)d_out : B, last);
    hin = B;
  }
}